// Round 1
// baseline (457.844 us; speedup 1.0000x reference)
//
#include <hip/hip_runtime.h>

// LJ pair energy, fused edge->molecule scatter.
// Constants from reference: R_EQ=1, WELL_DEPTH=1, CUTOFF=2.5, HEAL=0.5.
#define RCUT   2.5f
#define RIN    2.0f   // CUTOFF - HEAL
#define INVH   2.0f   // 1/HEAL

__device__ __forceinline__ float lj_edge(float x, float y, float z) {
    float r2 = fmaf(x, x, fmaf(y, y, z * z));
    float r  = sqrtf(r2);
    if (r > RCUT) return 0.0f;                 // switch == 0 exactly
    float inv2 = 1.0f / r2;                    // (R_EQ/r)^2 with R_EQ=1
    float p6   = inv2 * inv2 * inv2;
    float sw   = 1.0f;
    if (r > RIN) {
        float t = (r - RIN) * INVH;
        sw = fmaf(t * t, fmaf(2.0f, t, -3.0f), 1.0f);   // 1 + t^2*(2t-3)
    }
    return (p6 * p6 - p6) * sw;
}

__global__ __launch_bounds__(256) void zero_out(float* __restrict__ out, int n) {
    int i = blockIdx.x * 256 + threadIdx.x;
    if (i < n) out[i] = 0.0f;
}

// One thread processes 4 edges per grid-stride step:
//   3x float4 (vec_ij) + 1x int4 (idx_i), all 16B-aligned & coalesced.
// Per-block LDS histogram of n_mol bins, flushed once with global atomics.
__global__ __launch_bounds__(256) void lj_kernel(
    const float4* __restrict__ vec4,
    const int4*   __restrict__ idx4,
    const int*    __restrict__ idx_m,
    float*        __restrict__ out,
    int n_groups,          // n_edges / 4
    int n_mol,
    const float*  __restrict__ vec,     // scalar views for tail
    const int*    __restrict__ idx_i,
    int n_edges)
{
    extern __shared__ float bins[];
    for (int i = threadIdx.x; i < n_mol; i += 256) bins[i] = 0.0f;
    __syncthreads();

    const int tid      = blockIdx.x * 256 + threadIdx.x;
    const int nthreads = gridDim.x * 256;

    for (int g = tid; g < n_groups; g += nthreads) {
        float4 a = vec4[3 * g + 0];
        float4 b = vec4[3 * g + 1];
        float4 c = vec4[3 * g + 2];
        int4   ii = idx4[g];

        float y0 = lj_edge(a.x, a.y, a.z);
        float y1 = lj_edge(a.w, b.x, b.y);
        float y2 = lj_edge(b.z, b.w, c.x);
        float y3 = lj_edge(c.y, c.z, c.w);

        if (y0 != 0.0f) atomicAdd(&bins[idx_m[ii.x]], y0);
        if (y1 != 0.0f) atomicAdd(&bins[idx_m[ii.y]], y1);
        if (y2 != 0.0f) atomicAdd(&bins[idx_m[ii.z]], y2);
        if (y3 != 0.0f) atomicAdd(&bins[idx_m[ii.w]], y3);
    }

    // tail (n_edges % 4), normally empty for E = 20M
    for (int e = 4 * n_groups + tid; e < n_edges; e += nthreads) {
        float x = vec[3 * e], y = vec[3 * e + 1], z = vec[3 * e + 2];
        float v = lj_edge(x, y, z);
        if (v != 0.0f) atomicAdd(&bins[idx_m[idx_i[e]]], v);
    }

    __syncthreads();
    for (int i = threadIdx.x; i < n_mol; i += 256) {
        float v = bins[i];
        if (v != 0.0f) atomicAdd(&out[i], 0.5f * v);   // WELL_DEPTH * 0.5
    }
}

extern "C" void kernel_launch(void* const* d_in, const int* in_sizes, int n_in,
                              void* d_out, int out_size, void* d_ws, size_t ws_size,
                              hipStream_t stream) {
    const float* vec   = (const float*)d_in[0];
    // d_in[1] (positions) only provides a shape in the reference -> unused.
    const int*   idx_i = (const int*)d_in[2];
    const int*   idx_m = (const int*)d_in[3];
    float*       out   = (float*)d_out;

    const int n_edges  = in_sizes[2];
    const int n_mol    = out_size;
    const int n_groups = n_edges / 4;

    zero_out<<<(n_mol + 255) / 256, 256, 0, stream>>>(out, n_mol);

    const int nb = 2048;                       // 8 blocks/CU target, grid-stride
    const size_t lds = (size_t)n_mol * sizeof(float);
    lj_kernel<<<nb, 256, lds, stream>>>(
        (const float4*)vec, (const int4*)idx_i, idx_m, out,
        n_groups, n_mol, vec, idx_i, n_edges);
}

// Round 2
// 423.781 us; speedup vs baseline: 1.0804x; 1.0804x over previous
//
#include <hip/hip_runtime.h>

// LJ pair energy, fused edge->molecule scatter.
// R_EQ=1, WELL_DEPTH=1, CUTOFF=2.5, HEAL=0.5.
#define RCUT   2.5f
#define RIN    2.0f   // CUTOFF - HEAL
#define INVH   2.0f   // 1/HEAL

#define BT     512                  // threads per block (main kernel)
#define CHUNK  (BT * 4)             // edges per chunk = 2048
#define NF4    (CHUNK * 3 / 4)      // float4s per chunk = 1536

__device__ __forceinline__ float lj_edge(float x, float y, float z) {
    float r2 = fmaf(x, x, fmaf(y, y, z * z));
    float r  = sqrtf(r2);
    if (r > RCUT) return 0.0f;                 // switch == 0 exactly
    float inv2 = 1.0f / r2;                    // (R_EQ/r)^2
    float p6   = inv2 * inv2 * inv2;
    float sw   = 1.0f;
    if (r > RIN) {
        float t = (r - RIN) * INVH;
        sw = fmaf(t * t, fmaf(2.0f, t, -3.0f), 1.0f);   // 1 + t^2*(2t-3)
    }
    return (p6 * p6 - p6) * sw;
}

// binary search over sorted boundaries in LDS: returns m with b[m] <= a < b[m+1]
__device__ __forceinline__ int mol_of(const int* __restrict__ b, int a, int kiter) {
    int lo = 0, hi = 0;   // hi set by caller convention below
    return lo + hi; // unused
}

__device__ __forceinline__ int bsearch_lds(const int* __restrict__ b, int a,
                                           int n_mol, int kiter) {
    int lo = 0, hi = n_mol;
    #pragma unroll 10
    for (int k = 0; k < kiter; ++k) {
        int mid = (lo + hi) >> 1;
        if (a >= b[mid]) lo = mid; else hi = mid;
    }
    return lo;
}

__global__ __launch_bounds__(256) void zero_out(float* __restrict__ out, int n) {
    int i = blockIdx.x * 256 + threadIdx.x;
    if (i < n) out[i] = 0.0f;
}

// Build molecule start offsets from sorted idx_m: start[m] = first atom of mol m,
// start[n_mol] = n_atoms. Handles (absent) empty molecules via range fill.
__global__ __launch_bounds__(256) void build_bounds(
    const int* __restrict__ idx_m, int* __restrict__ start, int n_atoms, int n_mol) {
    int a = blockIdx.x * 256 + threadIdx.x;
    if (a >= n_atoms) return;
    int m  = idx_m[a];
    int pm = (a == 0) ? -1 : idx_m[a - 1];
    for (int mm = pm + 1; mm <= m; ++mm) start[mm] = a;
    if (a == n_atoms - 1)
        for (int mm = m + 1; mm <= n_mol; ++mm) start[mm] = n_atoms;
}

__global__ __launch_bounds__(BT) void lj_main(
    const float4* __restrict__ vec4,
    const int4*   __restrict__ idx4,
    const int*    __restrict__ bounds_g,   // n_mol+1
    const float*  __restrict__ vec,        // scalar view for tail
    const int*    __restrict__ idx_i,
    float*        __restrict__ out,
    int n_edges, int n_mol, int kiter)
{
    extern __shared__ char smem[];
    float4* stage  = (float4*)smem;                         // NF4 (16B aligned)
    float*  bins   = (float*)(smem + NF4 * 16);             // n_mol
    int*    bounds = (int*)(smem + NF4 * 16 + n_mol * 4);   // n_mol+1

    for (int i = threadIdx.x; i < n_mol; i += BT) bins[i] = 0.0f;
    for (int i = threadIdx.x; i <= n_mol; i += BT) bounds[i] = bounds_g[i];
    __syncthreads();

    const int n_g     = n_edges >> 2;        // 4-edge groups
    const int nf4_tot = n_g * 3;             // float4s covering those groups
    const int nchunks = (n_g + BT - 1) / BT;
    const int t = threadIdx.x;

    for (int ch = blockIdx.x; ch < nchunks; ch += gridDim.x) {
        const int gbase = ch * BT;
        const int fb    = gbase * 3;
        // perfectly coalesced stage: lane t loads float4 fb + j*BT + t
        #pragma unroll
        for (int j = 0; j < 3; ++j) {
            int fi = fb + j * BT + t;
            if (fi < nf4_tot) stage[j * BT + t] = vec4[fi];
        }
        __syncthreads();

        const int g = gbase + t;
        if (g < n_g) {
            // conflict-free ds_read_b128 x3 (stride 48 B)
            float4 A = stage[3 * t + 0];
            float4 B = stage[3 * t + 1];
            float4 C = stage[3 * t + 2];
            int4  ii = idx4[g];

            float y0 = lj_edge(A.x, A.y, A.z);
            float y1 = lj_edge(A.w, B.x, B.y);
            float y2 = lj_edge(B.z, B.w, C.x);
            float y3 = lj_edge(C.y, C.z, C.w);

            if (y0 != 0.0f) atomicAdd(&bins[bsearch_lds(bounds, ii.x, n_mol, kiter)], y0);
            if (y1 != 0.0f) atomicAdd(&bins[bsearch_lds(bounds, ii.y, n_mol, kiter)], y1);
            if (y2 != 0.0f) atomicAdd(&bins[bsearch_lds(bounds, ii.z, n_mol, kiter)], y2);
            if (y3 != 0.0f) atomicAdd(&bins[bsearch_lds(bounds, ii.w, n_mol, kiter)], y3);
        }
        __syncthreads();
    }

    // leftover edges (n_edges % 4) — block 0 only
    if (blockIdx.x == 0 && t < (n_edges & 3)) {
        int e = 4 * n_g + t;
        float v = lj_edge(vec[3 * e], vec[3 * e + 1], vec[3 * e + 2]);
        if (v != 0.0f) atomicAdd(&bins[bsearch_lds(bounds, idx_i[e], n_mol, kiter)], v);
    }
    __syncthreads();

    for (int i = threadIdx.x; i < n_mol; i += BT) {
        float v = bins[i];
        if (v != 0.0f) atomicAdd(&out[i], 0.5f * v);   // WELL_DEPTH * 0.5
    }
}

extern "C" void kernel_launch(void* const* d_in, const int* in_sizes, int n_in,
                              void* d_out, int out_size, void* d_ws, size_t ws_size,
                              hipStream_t stream) {
    const float* vec   = (const float*)d_in[0];
    const int*   idx_i = (const int*)d_in[2];
    const int*   idx_m = (const int*)d_in[3];
    float*       out   = (float*)d_out;

    const int n_edges = in_sizes[2];
    const int n_atoms = in_sizes[3];
    const int n_mol   = out_size;

    int* start = (int*)d_ws;            // (n_mol+1) ints

    zero_out<<<(n_mol + 255) / 256, 256, 0, stream>>>(out, n_mol);
    build_bounds<<<(n_atoms + 255) / 256, 256, 0, stream>>>(idx_m, start, n_atoms, n_mol);

    int kiter = 0;
    while ((1 << kiter) < n_mol) ++kiter;   // 10 for n_mol=1000

    const int    nb  = 1024;
    const size_t lds = (size_t)NF4 * 16 + (size_t)n_mol * 4 + (size_t)(n_mol + 1) * 4;
    lj_main<<<nb, BT, lds, stream>>>(
        (const float4*)vec, (const int4*)idx_i, start,
        vec, idx_i, out, n_edges, n_mol, kiter);
}

// Round 3
// 408.624 us; speedup vs baseline: 1.1205x; 1.0371x over previous
//
#include <hip/hip_runtime.h>

// LJ pair energy, fused edge->molecule scatter.
// R_EQ=1, WELL_DEPTH=1, CUTOFF=2.5, HEAL=0.5.
#define RCUT   2.5f
#define RIN    2.0f   // CUTOFF - HEAL
#define INVH   2.0f   // 1/HEAL

#define BT     512                  // threads per block (main kernel)
#define NF4    (BT * 3)             // float4s staged per chunk (BT groups x 3)

__device__ __forceinline__ float lj_edge(float x, float y, float z) {
    float r2 = fmaf(x, x, fmaf(y, y, z * z));
    float r  = sqrtf(r2);
    if (r > RCUT) return 0.0f;                 // switch == 0 exactly
    float inv2 = 1.0f / r2;                    // (R_EQ/r)^2
    float p6   = inv2 * inv2 * inv2;
    float sw   = 1.0f;
    if (r > RIN) {
        float t = (r - RIN) * INVH;
        sw = fmaf(t * t, fmaf(2.0f, t, -3.0f), 1.0f);   // 1 + t^2*(2t-3)
    }
    return (p6 * p6 - p6) * sw;
}

// mol of atom a. Fast path (uni): magic-multiply divide, exact for
// q = a*n_mol < 2^31 (host-verified). Fallback: guess + linear fixup on
// LDS bounds (correct for any sorted idx_m, incl. empty molecules).
__device__ __forceinline__ int mol_of(int a, int n_mol,
                                      unsigned long long M, int sh,
                                      bool uni, const int* __restrict__ bounds) {
    unsigned q = (unsigned)a * (unsigned)n_mol;
    int g = (int)(((unsigned long long)q * M) >> sh);
    if (!uni) {
        if (g > n_mol - 1) g = n_mol - 1;
        if (g < 0) g = 0;
        while (g > 0 && a < bounds[g]) --g;
        while (g < n_mol - 1 && a >= bounds[g + 1]) ++g;
    }
    return g;
}

// zero out[] and init uniform-flag
__global__ __launch_bounds__(256) void init_k(float* __restrict__ out, int n_mol,
                                              int* __restrict__ flag, int flag_init) {
    int i = blockIdx.x * 256 + threadIdx.x;
    if (i < n_mol) out[i] = 0.0f;
    if (i == 0) *flag = flag_init;
}

// Build molecule start offsets from sorted idx_m, and verify idx_m matches the
// uniform formula (a*n_mol)/n_atoms (u64 div = ground truth).
__global__ __launch_bounds__(256) void build_bounds(
    const int* __restrict__ idx_m, int* __restrict__ start,
    int* __restrict__ flag, int n_atoms, int n_mol) {
    int a = blockIdx.x * 256 + threadIdx.x;
    if (a >= n_atoms) return;
    int m  = idx_m[a];
    int pm = (a == 0) ? -1 : idx_m[a - 1];
    for (int mm = pm + 1; mm <= m; ++mm) start[mm] = a;
    if (a == n_atoms - 1)
        for (int mm = m + 1; mm <= n_mol; ++mm) start[mm] = n_atoms;
    int mf = (int)(((unsigned long long)(unsigned)a * (unsigned)n_mol) / (unsigned)n_atoms);
    if (m != mf) atomicAnd(flag, 0);
}

__global__ __launch_bounds__(BT) void lj_main(
    const float4* __restrict__ vec4,
    const int4*   __restrict__ idx4,
    const int*    __restrict__ bounds_g,   // n_mol+1
    const int*    __restrict__ flag,
    const float*  __restrict__ vec,        // scalar view for tail
    const int*    __restrict__ idx_i,
    float*        __restrict__ out,
    int n_edges, int n_mol,
    unsigned long long M, int sh)
{
    extern __shared__ char smem[];
    float4* stage  = (float4*)smem;                         // NF4 float4s
    float*  bins   = (float*)(smem + NF4 * 16);             // n_mol
    int*    bounds = (int*)(smem + NF4 * 16 + n_mol * 4);   // n_mol+1

    for (int i = threadIdx.x; i < n_mol; i += BT) bins[i] = 0.0f;
    for (int i = threadIdx.x; i <= n_mol; i += BT) bounds[i] = bounds_g[i];
    const bool uni = (*flag != 0);                          // wave-uniform
    __syncthreads();

    const int n_g     = n_edges >> 2;        // 4-edge groups
    const int nf4_tot = n_g * 3;
    const int nchunks = (n_g + BT - 1) / BT;
    const int t = threadIdx.x;

    for (int ch = blockIdx.x; ch < nchunks; ch += gridDim.x) {
        const int gbase = ch * BT;
        const int fb    = gbase * 3;
        #pragma unroll
        for (int j = 0; j < 3; ++j) {       // perfectly coalesced stage
            int fi = fb + j * BT + t;
            if (fi < nf4_tot) stage[j * BT + t] = vec4[fi];
        }
        __syncthreads();

        const int g = gbase + t;
        if (g < n_g) {
            float4 A = stage[3 * t + 0];    // 48B stride: disjoint 4-bank
            float4 B = stage[3 * t + 1];    // windows -> at LDS BW floor
            float4 C = stage[3 * t + 2];
            int4  ii = idx4[g];             // coalesced 16B/lane

            float y0 = lj_edge(A.x, A.y, A.z);
            float y1 = lj_edge(A.w, B.x, B.y);
            float y2 = lj_edge(B.z, B.w, C.x);
            float y3 = lj_edge(C.y, C.z, C.w);

            if (y0 != 0.0f) atomicAdd(&bins[mol_of(ii.x, n_mol, M, sh, uni, bounds)], y0);
            if (y1 != 0.0f) atomicAdd(&bins[mol_of(ii.y, n_mol, M, sh, uni, bounds)], y1);
            if (y2 != 0.0f) atomicAdd(&bins[mol_of(ii.z, n_mol, M, sh, uni, bounds)], y2);
            if (y3 != 0.0f) atomicAdd(&bins[mol_of(ii.w, n_mol, M, sh, uni, bounds)], y3);
        }
        __syncthreads();
    }

    // leftover edges (n_edges % 4) — block 0 only
    if (blockIdx.x == 0 && t < (n_edges & 3)) {
        int e = 4 * n_g + t;
        float v = lj_edge(vec[3 * e], vec[3 * e + 1], vec[3 * e + 2]);
        if (v != 0.0f) atomicAdd(&bins[mol_of(idx_i[e], n_mol, M, sh, uni, bounds)], v);
    }
    __syncthreads();

    // rotated flush: blocks start at different bins to spread atomic contention
    int off = (int)((blockIdx.x * 131u) % (unsigned)n_mol);
    for (int i = threadIdx.x; i < n_mol; i += BT) {
        int j = i + off; if (j >= n_mol) j -= n_mol;
        float v = bins[j];
        if (v != 0.0f) atomicAdd(&out[j], 0.5f * v);   // WELL_DEPTH * 0.5
    }
}

extern "C" void kernel_launch(void* const* d_in, const int* in_sizes, int n_in,
                              void* d_out, int out_size, void* d_ws, size_t ws_size,
                              hipStream_t stream) {
    const float* vec   = (const float*)d_in[0];
    const int*   idx_i = (const int*)d_in[2];
    const int*   idx_m = (const int*)d_in[3];
    float*       out   = (float*)d_out;

    const int n_edges = in_sizes[2];
    const int n_atoms = in_sizes[3];
    const int n_mol   = out_size;

    int* start = (int*)d_ws;                  // n_mol+1 ints
    int* flag  = (int*)d_ws + (n_mol + 2);    // 1 int

    // magic divisor for q/n_atoms, q = a*n_mol < 2^31:
    // M = 2^sh/d + 1; exact for all q < 2^31 iff e = M*d - 2^sh <= 2^(sh-31)
    unsigned d = (unsigned)n_atoms;
    unsigned long long M = 1; int sh = 32;
    bool ok = ((unsigned long long)(unsigned)n_mol * d) <= 0x7fffffffull;
    if (ok) {
        bool found = false;
        for (sh = 32; sh <= 62; ++sh) {
            unsigned long long tk = 1ull << sh;
            M = tk / d + 1;
            unsigned long long e = M * d - tk;
            if (e <= (1ull << (sh - 31))) { found = true; break; }
        }
        ok = found;
    }
    if (!ok) { M = 0; sh = 0; }               // forces fallback path

    init_k<<<(n_mol + 255) / 256, 256, 0, stream>>>(out, n_mol, flag, ok ? 1 : 0);
    build_bounds<<<(n_atoms + 255) / 256, 256, 0, stream>>>(idx_m, start, flag, n_atoms, n_mol);

    const int    nb  = 1024;                  // 4 blocks/CU (LDS-limited), full chip
    const size_t lds = (size_t)NF4 * 16 + (size_t)n_mol * 4 + (size_t)(n_mol + 1) * 4;
    lj_main<<<nb, BT, lds, stream>>>(
        (const float4*)vec, (const int4*)idx_i, start, flag,
        vec, idx_i, out, n_edges, n_mol, M, sh);
}

// Round 4
// 399.391 us; speedup vs baseline: 1.1464x; 1.0231x over previous
//
#include <hip/hip_runtime.h>

// LJ pair energy, fused edge->molecule scatter. One lane = one edge.
// R_EQ=1, WELL_DEPTH=1, CUTOFF=2.5, HEAL=0.5.
#define RCUT2  6.25f    // CUTOFF^2
#define RIN2   4.0f     // (CUTOFF-HEAL)^2
#define BT     512

struct __attribute__((aligned(4))) F3 { float x, y, z; };   // 12 B, no padding

// zero out[] and init uniform-flag
__global__ __launch_bounds__(256) void init_k(float* __restrict__ out, int n_mol,
                                              int* __restrict__ flag, int flag_init) {
    int i = blockIdx.x * 256 + threadIdx.x;
    if (i < n_mol) out[i] = 0.0f;
    if (i == 0) *flag = flag_init;
}

// Build molecule start offsets from sorted idx_m; verify idx_m matches the
// uniform formula (a*n_mol)/n_atoms (u64 div = ground truth).
__global__ __launch_bounds__(256) void build_bounds(
    const int* __restrict__ idx_m, int* __restrict__ start,
    int* __restrict__ flag, int n_atoms, int n_mol) {
    int a = blockIdx.x * 256 + threadIdx.x;
    if (a >= n_atoms) return;
    int m  = idx_m[a];
    int pm = (a == 0) ? -1 : idx_m[a - 1];
    for (int mm = pm + 1; mm <= m; ++mm) start[mm] = a;
    if (a == n_atoms - 1)
        for (int mm = m + 1; mm <= n_mol; ++mm) start[mm] = n_atoms;
    int mf = (int)(((unsigned long long)(unsigned)a * (unsigned)n_mol) / (unsigned)n_atoms);
    if (m != mf) atomicAnd(flag, 0);
}

__global__ __launch_bounds__(BT) void lj_direct(
    const F3*  __restrict__ vec3,
    const int* __restrict__ idx_i,
    const int* __restrict__ bounds_g,   // n_mol+1 (global; fallback only)
    const int* __restrict__ flag,
    float*     __restrict__ out,
    int n_edges, int n_mol,
    unsigned long long M, int sh)
{
    extern __shared__ float bins[];     // n_mol fp32
    for (int i = threadIdx.x; i < n_mol; i += BT) bins[i] = 0.0f;
    const bool uni = (*flag != 0);      // wave-uniform
    __syncthreads();

    const int stride = gridDim.x * BT;
    for (int e = blockIdx.x * BT + threadIdx.x; e < n_edges; e += stride) {
        F3  v = vec3[e];                // 12 B/lane -> global_load_dwordx3
        int a = idx_i[e];               // 4 B/lane, coalesced

        float r2 = fmaf(v.x, v.x, fmaf(v.y, v.y, v.z * v.z));
        if (r2 > RCUT2) continue;       // switch == 0 exactly

        float inv2 = __builtin_amdgcn_rcpf(r2);     // v_rcp_f32 (tol >> 1 ulp)
        float p6   = inv2 * inv2 * inv2;
        float y    = fmaf(p6, p6, -p6); // p12 - p6

        // switch (branchless): t = 2r - 4, sw = 1 + t^2 (2t - 3)
        float r  = __builtin_amdgcn_sqrtf(r2);
        float t  = fmaf(2.0f, r, -4.0f);
        float sw = fmaf(t * t, fmaf(2.0f, t, -3.0f), 1.0f);
        y *= (r2 > RIN2) ? sw : 1.0f;

        // molecule of atom a: magic-multiply divide (host-verified exact)
        unsigned q = (unsigned)a * (unsigned)n_mol;
        int m = (int)(((unsigned long long)q * M) >> sh);
        if (!uni) {                     // general sorted-idx_m fallback
            if (m > n_mol - 1) m = n_mol - 1;
            if (m < 0) m = 0;
            while (m > 0 && a < bounds_g[m]) --m;
            while (m < n_mol - 1 && a >= bounds_g[m + 1]) ++m;
        }
        atomicAdd(&bins[m], y);
    }

    __syncthreads();
    // rotated flush spreads global-atomic contention across bins
    unsigned off = (blockIdx.x * 131u) % (unsigned)n_mol;
    for (int i = threadIdx.x; i < n_mol; i += BT) {
        int j = i + (int)off; if (j >= n_mol) j -= n_mol;
        float bv = bins[j];
        if (bv != 0.0f) atomicAdd(&out[j], 0.5f * bv);   // WELL_DEPTH * 0.5
    }
}

extern "C" void kernel_launch(void* const* d_in, const int* in_sizes, int n_in,
                              void* d_out, int out_size, void* d_ws, size_t ws_size,
                              hipStream_t stream) {
    const float* vec   = (const float*)d_in[0];
    const int*   idx_i = (const int*)d_in[2];
    const int*   idx_m = (const int*)d_in[3];
    float*       out   = (float*)d_out;

    const int n_edges = in_sizes[2];
    const int n_atoms = in_sizes[3];
    const int n_mol   = out_size;

    int* start = (int*)d_ws;                  // n_mol+1 ints
    int* flag  = (int*)d_ws + (n_mol + 2);    // 1 int

    // magic divisor for q/n_atoms, q = a*n_mol < 2^31:
    // M = 2^sh/d + 1; exact for all q < 2^31 iff M*d - 2^sh <= 2^(sh-31)
    unsigned d = (unsigned)n_atoms;
    unsigned long long M = 1; int sh = 32;
    bool ok = ((unsigned long long)(unsigned)n_mol * d) <= 0x7fffffffull;
    if (ok) {
        bool found = false;
        for (sh = 32; sh <= 62; ++sh) {
            unsigned long long tk = 1ull << sh;
            M = tk / d + 1;
            unsigned long long e = M * d - tk;
            if (e <= (1ull << (sh - 31))) { found = true; break; }
        }
        ok = found;
    }
    if (!ok) { M = 0; sh = 0; }               // forces fallback path

    init_k<<<(n_mol + 255) / 256, 256, 0, stream>>>(out, n_mol, flag, ok ? 1 : 0);
    build_bounds<<<(n_atoms + 255) / 256, 256, 0, stream>>>(idx_m, start, flag, n_atoms, n_mol);

    const int    nb  = 1024;                  // 4 blocks/CU x 512 = 32 waves/CU
    const size_t lds = (size_t)n_mol * sizeof(float);
    lj_direct<<<nb, BT, lds, stream>>>(
        (const F3*)vec, idx_i, start, flag, out, n_edges, n_mol, M, sh);
}